// Round 9
// baseline (380.917 us; speedup 1.0000x reference)
//
#include <hip/hip_runtime.h>
#include <math.h>

#define D_MODEL 1024
#define NHEAD 16
#define HEAD_DIM 64
#define BATCH 2
#define SEQ 1024
#define ROWS (BATCH * SEQ)        // 2048
#define RD (ROWS * D_MODEL)       // 2097152
#define WSZ (D_MODEL * D_MODEL)   // 1048576
#define CHUNK 64
#define NCHUNK (SEQ / CHUNK)      // 16

typedef __attribute__((ext_vector_type(8))) short bf16x8;
typedef __attribute__((ext_vector_type(8))) _Float16 f16x8;
typedef __attribute__((ext_vector_type(8))) unsigned short ushort8;
typedef __attribute__((ext_vector_type(4))) unsigned short us4;
typedef __attribute__((ext_vector_type(4))) float f32x4;
typedef __attribute__((ext_vector_type(4))) unsigned int uint4v;
typedef unsigned short ushort;

// ---------------------------------------------------------------------------
// helpers
// ---------------------------------------------------------------------------
__device__ __forceinline__ void load_lds_16u(const unsigned short* g, unsigned short* l) {
    __builtin_amdgcn_global_load_lds((const __attribute__((address_space(1))) void*)g,
                                     (__attribute__((address_space(3))) void*)l, 16, 0, 0);
}
// fp32 -> bf16 RNE, and back (scan-internal precision scheme + fallback GEMM)
__device__ __forceinline__ unsigned short f2bf(float x) {
    unsigned int u = __float_as_uint(x);
    unsigned int r = (u + 0x7FFFu + ((u >> 16) & 1u)) >> 16;
    return (unsigned short)r;
}
__device__ __forceinline__ float bf2f(unsigned short h) {
    return __uint_as_float(((unsigned int)h) << 16);
}
// fp32 -> fp16 RNE (GEMM path)
__device__ __forceinline__ unsigned short f2h(float x) {
    _Float16 h = (_Float16)x;
    return __builtin_bit_cast(unsigned short, h);
}
// uniform-lane broadcast (SALU path, not LDS)
__device__ __forceinline__ float lane_bcast(float v, int lane) {
    return __uint_as_float(__builtin_amdgcn_readlane(__float_as_uint(v), lane));
}
// fragment-order index (SUBST=512 validated; no swizzle — R4 showed swizzle
// cuts conflicts but regresses time on the latency-critical chain)
#define SUBST 512
#define FBUF (8 * SUBST * 2)   // 8192 bytes per 64x64 operand buffer
__device__ __forceinline__ int fidx(int r, int k) {
    return ((r >> 4) * 2 + (k >> 5)) * SUBST + ((((k & 31) >> 3) << 4) + (r & 15)) * 8 + (k & 7);
}

// ---------------------------------------------------------------------------
// R9: GEMM tiles 128x64 -> 128x128 (qkv + final). Structure is a clone of two
// VALIDATED kernels: tile/acc/epilogue mapping from gemm_mfma (fallback), and
// chunk-staging (global_load_lds, chunk*512 + lane*8 readback) from the R5
// gemm_core_f16. A-staging bytes halve; MFMA:stage ratio 8:3 -> 16:4. At 128
// cols each wave's 64-col half = exactly one head, so the fused q/k L2-norm
// is wave-local (butterfly only, no LDS combine). Scan verbatim R8/v6.
// ---------------------------------------------------------------------------

// split: fp32 -> fp16 buffer. n4 = n/4 float4 groups.
__global__ __launch_bounds__(256) void split_kernel(const float* __restrict__ X,
                                                    unsigned short* __restrict__ H,
                                                    int n4) {
    int i = blockIdx.x * 256 + threadIdx.x;
    if (i >= n4) return;
    float4 v = ((const float4*)X)[i];
    us4 h;
    h.x = f2h(v.x); h.y = f2h(v.y); h.z = f2h(v.z); h.w = f2h(v.w);
    ((us4*)H)[i] = h;
}

// fused 4-way weight convert (one launch for Wq, Wk, Wv, Wo)
__global__ __launch_bounds__(256) void split4_kernel(const float* __restrict__ W0,
                                                     const float* __restrict__ W1,
                                                     const float* __restrict__ W2,
                                                     const float* __restrict__ W3,
                                                     unsigned short* __restrict__ H0,
                                                     unsigned short* __restrict__ H1,
                                                     unsigned short* __restrict__ H2,
                                                     unsigned short* __restrict__ H3) {
    const int n4 = WSZ / 4;
    int i = blockIdx.x * 256 + threadIdx.x;
    const int which = i / n4;
    const int j = i - which * n4;
    const float* X = (which == 0) ? W0 : (which == 1) ? W1 : (which == 2) ? W2 : W3;
    unsigned short* H = (which == 0) ? H0 : (which == 1) ? H1 : (which == 2) ? H2 : H3;
    float4 v = ((const float4*)X)[j];
    us4 h;
    h.x = f2h(v.x); h.y = f2h(v.y); h.z = f2h(v.z); h.w = f2h(v.w);
    ((us4*)H)[j] = h;
}

// ---------------------------------------------------------------------------
// GEMM core, fp16 single-product, 128x128 tile, 256 threads / 4 waves.
// Tiling identical to the validated gemm_mfma fallback; staging identical to
// the validated R5 gemm_core_f16 (16 chunks of 16row x 32col per K-step).
// DO_NORM: per-row L2 norm over each 64-col half (one head per wave, wave-local).
// ---------------------------------------------------------------------------
template <int ACT, int DO_NORM>
__device__ __forceinline__ void gemm_core128(const unsigned short* __restrict__ Ah,
                                             const unsigned short* __restrict__ Bh,
                                             float* __restrict__ C,
                                             int M, int N, int K,
                                             unsigned short* LA0, unsigned short* LB0) {
    const int t = threadIdx.x;
    const int wave = t >> 6, lane = t & 63;
    const int wm = wave >> 1, wn = wave & 1;
    const int m16 = lane & 15, kg = lane >> 4;
    const int row0 = blockIdx.y * 128, col0 = blockIdx.x * 128;

    f32x4 acc[4][4];
#pragma unroll
    for (int i = 0; i < 4; ++i)
#pragma unroll
        for (int j = 0; j < 4; ++j) acc[i][j] = (f32x4){0.f, 0.f, 0.f, 0.f};

    for (int k0 = 0; k0 < K; k0 += 32) {
#pragma unroll
        for (int ci = 0; ci < 4; ++ci) {
            const int c = wave * 4 + ci;   // 0..15
            const unsigned short* src;
            unsigned short* dst;
            int g16, rbase;
            if (c < 8) { src = Ah; dst = &LA0[c * 512];       g16 = c;     rbase = row0; }
            else       { src = Bh; dst = &LB0[(c - 8) * 512]; g16 = c - 8; rbase = col0; }
            const unsigned short* gp = src + (size_t)(rbase + g16 * 16 + m16) * K + k0 + kg * 8;
            load_lds_16u(gp, dst);
        }
        __syncthreads();

        f16x8 fah[4], fbh[4];
#pragma unroll
        for (int i = 0; i < 4; ++i)
            fah[i] = *(const f16x8*)&LA0[(wm * 4 + i) * 512 + lane * 8];
#pragma unroll
        for (int j = 0; j < 4; ++j)
            fbh[j] = *(const f16x8*)&LB0[(wn * 4 + j) * 512 + lane * 8];
#pragma unroll
        for (int i = 0; i < 4; ++i)
#pragma unroll
            for (int j = 0; j < 4; ++j)
                acc[i][j] = __builtin_amdgcn_mfma_f32_16x16x32_f16(fah[i], fbh[j], acc[i][j], 0, 0, 0);
        __syncthreads();
    }

    // epilogue (in place on acc): activation -> optional per-head row L2 norm
    if (ACT == 1) {
#pragma unroll
        for (int i = 0; i < 4; ++i)
#pragma unroll
            for (int j = 0; j < 4; ++j)
#pragma unroll
                for (int rg = 0; rg < 4; ++rg) {
                    const float v = acc[i][j][rg];
                    acc[i][j][rg] = v / (1.f + expf(-v));
                }
    }
    if (DO_NORM) {
        // wave covers rows wm*64+i*16+kg*4+rg x cols wn*64 + (j*16+m16):
        // the 64-col span = one head, entirely within this wave (j x m16).
        // Butterfly stays within the 16-lane m16 group (kg untouched).
#pragma unroll
        for (int i = 0; i < 4; ++i)
#pragma unroll
            for (int rg = 0; rg < 4; ++rg) {
                float ss = 0.f;
#pragma unroll
                for (int j = 0; j < 4; ++j) ss += acc[i][j][rg] * acc[i][j][rg];
#pragma unroll
                for (int off = 8; off; off >>= 1) ss += __shfl_xor(ss, off);
                const float inv = 1.f / (sqrtf(ss) + 1e-6f);
#pragma unroll
                for (int j = 0; j < 4; ++j) acc[i][j][rg] *= inv;
            }
    }
#pragma unroll
    for (int i = 0; i < 4; ++i)
#pragma unroll
        for (int j = 0; j < 4; ++j) {
            const int rowb = row0 + wm * 64 + i * 16 + kg * 4;
            const int col  = col0 + wn * 64 + j * 16 + m16;
#pragma unroll
            for (int rg = 0; rg < 4; ++rg)
                C[(size_t)(rowb + rg) * N + col] = acc[i][j][rg];
        }
}

template <int ACT>
__global__ __launch_bounds__(256) void gemm_f16s(const unsigned short* __restrict__ Ah,
                                                 const unsigned short* __restrict__ Bh,
                                                 float* __restrict__ C,
                                                 int M, int N, int K) {
    __shared__ unsigned short LA[8 * 512];
    __shared__ unsigned short LB[8 * 512];
    gemm_core128<ACT, 0>(Ah, Bh, C, M, N, K, LA, LB);
}

// fused QKV GEMM: blockIdx.z selects weight/output; q/k rows L2-normalized
// in the epilogue (each 64-col wave-half = one head, wave-local reduction).
__global__ __launch_bounds__(256) void gemm_qkv(const unsigned short* __restrict__ Ah,
                                                const unsigned short* __restrict__ Bqh,
                                                const unsigned short* __restrict__ Bkh,
                                                const unsigned short* __restrict__ Bvh,
                                                float* __restrict__ Cq,
                                                float* __restrict__ Ck,
                                                float* __restrict__ Cv) {
    __shared__ unsigned short LA[8 * 512];
    __shared__ unsigned short LB[8 * 512];
    const int z = blockIdx.z;
    const unsigned short* Bh = (z == 0) ? Bqh : (z == 1) ? Bkh : Bvh;
    float* C = (z == 0) ? Cq : (z == 1) ? Ck : Cv;
    if (z < 2)
        gemm_core128<1, 1>(Ah, Bh, C, ROWS, D_MODEL, D_MODEL, LA, LB);
    else
        gemm_core128<1, 0>(Ah, Bh, C, ROWS, D_MODEL, D_MODEL, LA, LB);
}

// ---------------------------------------------------------------------------
// Fallback GEMM (inline bf16 split) — only if ws_size too small. Unchanged.
// ---------------------------------------------------------------------------
#define LDST 40
template <int ACT>
__global__ __launch_bounds__(256) void gemm_mfma(const float* __restrict__ A,
                                                 const float* __restrict__ B,
                                                 float* __restrict__ C,
                                                 int M, int N, int K) {
    __shared__ unsigned short Ahi[128 * LDST], Alo[128 * LDST];
    __shared__ unsigned short Bhi[128 * LDST], Blo[128 * LDST];

    const int t = threadIdx.x;
    const int wave = t >> 6, lane = t & 63;
    const int wm = wave >> 1, wn = wave & 1;
    const int row0 = blockIdx.y * 128, col0 = blockIdx.x * 128;
    const int sr = t >> 1;
    const int sh = t & 1;
    const int m16 = lane & 15, kg = lane >> 4;

    f32x4 acc[4][4];
#pragma unroll
    for (int i = 0; i < 4; ++i)
#pragma unroll
        for (int j = 0; j < 4; ++j) acc[i][j] = (f32x4){0.f, 0.f, 0.f, 0.f};

    const float* ga = A + (size_t)(row0 + sr) * K + sh * 16;
    const float* gb = B + (size_t)(col0 + sr) * K + sh * 16;
    const int sbase = sr * LDST + sh * 16;

    for (int k0 = 0; k0 < K; k0 += 32) {
        float af[16], bf[16];
#pragma unroll
        for (int i = 0; i < 4; ++i) {
            float4 a4 = *(const float4*)(ga + k0 + i * 4);
            float4 b4 = *(const float4*)(gb + k0 + i * 4);
            af[i * 4 + 0] = a4.x; af[i * 4 + 1] = a4.y; af[i * 4 + 2] = a4.z; af[i * 4 + 3] = a4.w;
            bf[i * 4 + 0] = b4.x; bf[i * 4 + 1] = b4.y; bf[i * 4 + 2] = b4.z; bf[i * 4 + 3] = b4.w;
        }
        ushort8 ah0, ah1, al0, al1, bh0, bh1, bl0, bl1;
#pragma unroll
        for (int j = 0; j < 8; ++j) {
            unsigned short h = f2bf(af[j]);       ah0[j] = h; al0[j] = f2bf(af[j] - bf2f(h));
            h = f2bf(af[j + 8]);                  ah1[j] = h; al1[j] = f2bf(af[j + 8] - bf2f(h));
            h = f2bf(bf[j]);                      bh0[j] = h; bl0[j] = f2bf(bf[j] - bf2f(h));
            h = f2bf(bf[j + 8]);                  bh1[j] = h; bl1[j] = f2bf(bf[j + 8] - bf2f(h));
        }
        *(ushort8*)&Ahi[sbase] = ah0;  *(ushort8*)&Ahi[sbase + 8] = ah1;
        *(ushort8*)&Alo[sbase] = al0;  *(ushort8*)&Alo[sbase + 8] = al1;
        *(ushort8*)&Bhi[sbase] = bh0;  *(ushort8*)&Bhi[sbase + 8] = bh1;
        *(ushort8*)&Blo[sbase] = bl0;  *(ushort8*)&Blo[sbase + 8] = bl1;
        __syncthreads();

        bf16x8 fah[4], fal[4], fbh[4], fbl[4];
#pragma unroll
        for (int i = 0; i < 4; ++i) {
            const int ar = (wm * 64 + i * 16 + m16) * LDST + kg * 8;
            const int br = (wn * 64 + i * 16 + m16) * LDST + kg * 8;
            fah[i] = *(const bf16x8*)&Ahi[ar];
            fal[i] = *(const bf16x8*)&Alo[ar];
            fbh[i] = *(const bf16x8*)&Bhi[br];
            fbl[i] = *(const bf16x8*)&Blo[br];
        }
#pragma unroll
        for (int i = 0; i < 4; ++i)
#pragma unroll
            for (int j = 0; j < 4; ++j) {
                acc[i][j] = __builtin_amdgcn_mfma_f32_16x16x32_bf16(fal[i], fbh[j], acc[i][j], 0, 0, 0);
                acc[i][j] = __builtin_amdgcn_mfma_f32_16x16x32_bf16(fah[i], fbl[j], acc[i][j], 0, 0, 0);
                acc[i][j] = __builtin_amdgcn_mfma_f32_16x16x32_bf16(fah[i], fbh[j], acc[i][j], 0, 0, 0);
            }
        __syncthreads();
    }

#pragma unroll
    for (int i = 0; i < 4; ++i)
#pragma unroll
        for (int j = 0; j < 4; ++j) {
            const int col = col0 + wn * 64 + j * 16 + m16;
            const int rowb = row0 + wm * 64 + i * 16 + kg * 4;
#pragma unroll
            for (int rg = 0; rg < 4; ++rg) {
                float v = acc[i][j][rg];
                if (ACT == 1) v = v / (1.f + expf(-v));
                C[(size_t)(rowb + rg) * N + col] = v;
            }
        }
}

// ---------------------------------------------------------------------------
// beta = 2*sigmoid(x @ Wb^T)  : (ROWS, NHEAD). One wave per row. (fp32)
// ---------------------------------------------------------------------------
__global__ __launch_bounds__(256) void beta_kernel(const float* __restrict__ x,
                                                   const float* __restrict__ Wb,
                                                   float* __restrict__ beta) {
    const int wave = blockIdx.x * 4 + (threadIdx.x >> 6);
    const int lane = threadIdx.x & 63;
    const float* xr = x + (size_t)wave * D_MODEL;
    float xv[16];
#pragma unroll
    for (int j = 0; j < 16; ++j) xv[j] = xr[lane + 64 * j];
    for (int n = 0; n < NHEAD; ++n) {
        const float* wr = Wb + (size_t)n * D_MODEL;
        float s = 0.f;
#pragma unroll
        for (int j = 0; j < 16; ++j) s += xv[j] * wr[lane + 64 * j];
#pragma unroll
        for (int off = 32; off; off >>= 1) s += __shfl_xor(s, off);
        if (lane == 0) beta[(size_t)wave * NHEAD + n] = 2.f / (1.f + expf(-s));
    }
}

// ---------------------------------------------------------------------------
// L2-normalize q and k per (row, head) over HEAD_DIM=64. (fallback path only)
// ---------------------------------------------------------------------------
__global__ __launch_bounds__(256) void norm_qk(float* __restrict__ Q,
                                               float* __restrict__ Kp) {
    const int TOT = ROWS * NHEAD;
    int wave = blockIdx.x * 4 + (threadIdx.x >> 6);
    const int lane = threadIdx.x & 63;
    float* T = (wave < TOT) ? Q : Kp;
    int w = (wave < TOT) ? wave : wave - TOT;
    float* p = T + (size_t)(w >> 4) * D_MODEL + (size_t)(w & 15) * HEAD_DIM;
    float v = p[lane];
    float ss = v * v;
#pragma unroll
    for (int off = 32; off; off >>= 1) ss += __shfl_xor(ss, off);
    p[lane] = v / (sqrtf(ss) + 1e-6f);
}

// ---------------------------------------------------------------------------
// Chunked delta-rule scan v6 — VALIDATED at 214.8-215.5 µs (R1/R5/R8), verbatim.
// R4's XOR swizzle cut bank conflicts 34% but regressed +9% (latency-bound).
// R6/R7's fp16 scheme NaN'd twice (cause not localizable). Do not touch.
//   Hazard audit (6 barriers/chunk):
//     V0/W union: V0 wr B1-B2, rd B2-B3; W zero+wr B3-B4 (wave0), rd B4-B5.
//     K/DT union: K wr stage, rd through B3-B4 (window QK); DT wr B4-B5,
//                 rd B5-B6.  Q: wr stage, rd B3-B4.  G: wr B3-B4, rd B5-B6.
//     M/MT: wr B5-B6, rd next chunk B1-B4.  C032: wr B2-B3, rd B3-B4.
// ---------------------------------------------------------------------------
#define SMEM_SCAN 156160   // 14*FBUF + 16640(C032) + 2*FBUF(A) + 4352(N32) + 4096(bAll)

__global__ __launch_bounds__(512, 1) void scan_chunked(const float* __restrict__ Qg,
                                                       const float* __restrict__ Kg,
                                                       const float* __restrict__ Vg,
                                                       const float* __restrict__ Btg,
                                                       float* __restrict__ Yg) {
    extern __shared__ char smem[];
    ushort* Mh_  = (ushort*)(smem + 0 * FBUF);
    ushort* Ml_  = (ushort*)(smem + 1 * FBUF);
    ushort* MTh_ = (ushort*)(smem + 2 * FBUF);
    ushort* MTl_ = (ushort*)(smem + 3 * FBUF);
    ushort* KTh_ = (ushort*)(smem + 4 * FBUF);
    ushort* KTl_ = (ushort*)(smem + 5 * FBUF);
    ushort* V0h_ = (ushort*)(smem + 6 * FBUF);   // union1: V0 / W
    ushort* V0l_ = (ushort*)(smem + 7 * FBUF);
    ushort* Wh_  = V0h_;
    ushort* Wl_  = V0l_;
    ushort* Gh_  = (ushort*)(smem + 8 * FBUF);
    ushort* Gl_  = (ushort*)(smem + 9 * FBUF);
    ushort* Kh_  = (ushort*)(smem + 10 * FBUF);  // union2: K / DT
    ushort* Kl_  = (ushort*)(smem + 11 * FBUF);
    ushort* DTh_ = Kh_;
    ushort* DTl_ = Kl_;
    ushort* Qh_  = (ushort*)(smem + 12 * FBUF);  // standalone
    ushort* Ql_  = (ushort*)(smem + 13 * FBUF);
    float*  C032 = (float*)(smem + 14 * FBUF);                     // 64x65 fp32 (16640 B)
    ushort* Ah_  = (ushort*)(smem + 14 * FBUF + 16640);
    ushort* Al_  = (ushort*)(smem + 15 * FBUF + 16640);
    float*  N32  = (float*)(smem + 16 * FBUF + 16640);             // 64x17 fp32 (4352 B)
    float*  bAll = (float*)(smem + 16 * FBUF + 16640 + 4352);      // 1024 fp32 (4096 B)

    const int b = blockIdx.x >> 4;
    const int n = blockIdx.x & 15;
    const int t = threadIdx.x;
    const int wave = t >> 6, lane = t & 63;
    const int wm = wave >> 1, wn = wave & 1;      // 4x2 wave grid (std tiling)
    const int m16 = lane & 15, kg = lane >> 4;
    const int bS = b * SEQ;
    const int nOff = n * HEAD_DIM;
    const int r = t >> 3, g = t & 7;   // staging: row r (0..63), col-octet g (0..7)

    // fp32 register state: row = wm*16 + kg*4 + rg, col = wn*32 + j*16 + m16
    f32x4 Macc[2];
    Macc[0] = (f32x4){0.f, 0.f, 0.f, 0.f};
    Macc[1] = (f32x4){0.f, 0.f, 0.f, 0.f};

    // ---- helpers ----
    auto load_af = [&](const ushort* Xh, const ushort* Xl, int tm, bf16x8* oh, bf16x8* ol) {
        const int lo8 = lane * 8;
#pragma unroll
        for (int half = 0; half < 2; ++half) {
            oh[half] = *(const bf16x8*)&Xh[(tm * 2 + half) * SUBST + lo8];
            ol[half] = *(const bf16x8*)&Xl[(tm * 2 + half) * SUBST + lo8];
        }
    };
    auto prod_cA = [&](const bf16x8* ah, const bf16x8* al,
                       const ushort* Bh, const ushort* Bl, int tn, f32x4* acc) {
        const int lo8 = lane * 8;
#pragma unroll
        for (int half = 0; half < 2; ++half) {
#pragma unroll
            for (int j = 0; j < 2; ++j) {
                const int jg = tn * 2 + j;
                bf16x8 bh = *(const bf16x8*)&Bh[(jg * 2 + half) * SUBST + lo8];
                bf16x8 bl = *(const bf16x8*)&Bl[(jg * 2 + half) * SUBST + lo8];
                acc[j] = __builtin_amdgcn_mfma_f32_16x16x32_bf16(al[half], bh, acc[j], 0, 0, 0);
                acc[j] = __builtin_amdgcn_mfma_f32_16x16x32_bf16(ah[half], bl, acc[j], 0, 0, 0);
                acc[j] = __builtin_amdgcn_mfma_f32_16x16x32_bf16(ah[half], bh, acc[j], 0, 0, 0);
            }
        }
    };

    // ---- one-time beta preload ----
    for (int i = t; i < SEQ; i += 512) bAll[i] = Btg[(size_t)(bS + i) * NHEAD + n];

    // ---- global prefetch registers (K,Q row-octets; V in std-tile layout) ----
    float4 pk0, pk1, pq0, pq1;
    float pv[8];
    auto issue_pf = [&](int cc) {
        const int so = cc * CHUNK;
        const float* gK = Kg + (size_t)(bS + so + r) * D_MODEL + nOff + g * 8;
        const float* gQ = Qg + (size_t)(bS + so + r) * D_MODEL + nOff + g * 8;
        pk0 = ((const float4*)gK)[0]; pk1 = ((const float4*)gK)[1];
        pq0 = ((const float4*)gQ)[0]; pq1 = ((const float4*)gQ)[1];
        const float* gV = Vg + (size_t)(bS + so) * D_MODEL + nOff;
#pragma unroll
        for (int j = 0; j < 2; ++j)
#pragma unroll
            for (int rg = 0; rg < 4; ++rg)
                pv[j * 4 + rg] = gV[(size_t)(wm * 16 + kg * 4 + rg) * D_MODEL + wn * 32 + j * 16 + m16];
    };
    issue_pf(0);

    for (int c = 0; c < NCHUNK; ++c) {
        const int s0 = c * CHUNK;

        // ---- stage K (+transpose), Q from prefetch regs ----
        {
            float kf[8] = {pk0.x, pk0.y, pk0.z, pk0.w, pk1.x, pk1.y, pk1.z, pk1.w};
            float qf[8] = {pq0.x, pq0.y, pq0.z, pq0.w, pq1.x, pq1.y, pq1.z, pq1.w};
            ushort8 kh8, kl8, qh8, ql8;
            ushort khv[8], klv[8];
#pragma unroll
            for (int e = 0; e < 8; ++e) {
                ushort h = f2bf(kf[e]);
                ushort l = f2bf(kf[e] - bf2f(h));
                khv[e] = h; klv[e] = l;
                kh8[e] = h; kl8[e] = l;
                h = f2bf(qf[e]); l = f2bf(qf[e] - bf2f(h));
                qh8[e] = h; ql8[e] = l;
            }
            const int o0 = fidx(r, g * 8);
            *(ushort8*)&Kh_[o0] = kh8;
            *(ushort8*)&Kl_[o0] = kl8;
            *(ushort8*)&Qh_[o0] = qh8;
            *(ushort8*)&Ql_[o0] = ql8;
#pragma unroll
            for (int e = 0; e < 8; ++e) {
                const int ib = fidx(g * 8 + e, r);
                KTh_[ib] = khv[e]; KTl_[ib] = klv[e];
            }
        }
        __syncthreads();   // B1

        bf16x8 kah[2], kal[2];     // cached K A-frags: live through P_C0
        f32x4 V0acc[2];
        {
            load_af(Kh_, Kl_, wm, kah, kal);
            // ---- P_R: V0 = V(reg) - K*M0^T ----
            V0acc[0] = (f32x4){0.f, 0.f, 0.f, 0.f};
            V0acc[1] = (f32x4){0.f, 0.f, 0.f, 0.f};
            if (c > 0) prod_cA(kah, kal, Mh_, Ml_, wn, V0acc);
#pragma unroll
            for (int j = 0; j < 2; ++j)
#pragma unroll
                for (int rg = 0; rg < 4; ++rg)
                    V0acc[j][rg] = pv[j * 4 + rg] - V0acc[j][rg];
            // V0 -> LDS (W-union buffer; wave 0 overwrites only after B3)
#pragma unroll
            for (int j = 0; j < 2; ++j)
#pragma unroll
                for (int rg = 0; rg < 4; ++rg) {
                    const int row = wm * 16 + kg * 4 + rg, col = wn * 32 + j * 16 + m16;
                    const float v0 = V0acc[j][rg];
                    const ushort h = f2bf(v0);
                    const int ii = fidx(row, col);
                    V0h_[ii] = h; V0l_[ii] = f2bf(v0 - bf2f(h));
                }
            // ---- P_A: A = K K^T (A-frags cached) ----
            f32x4 aacc[2];
            aacc[0] = (f32x4){0.f, 0.f, 0.f, 0.f};
            aacc[1] = (f32x4){0.f, 0.f, 0.f, 0.f};
            prod_cA(kah, kal, Kh_, Kl_, wn, aacc);
#pragma unroll
            for (int j = 0; j < 2; ++j)
#pragma unroll
                for (int rg = 0; rg < 4; ++rg) {
                    const int row = wm * 16 + kg * 4 + rg, col = wn * 32 + j * 16 + m16;
                    const float av = aacc[j][rg];
                    const ushort h = f2bf(av);
                    const int ii = fidx(row, col);
                    Ah_[ii] = h; Al_[ii] = f2bf(av - bf2f(h));
                }
        }
        __syncthreads();   // B2 (V0 + A visible)

        {
            // ---- P_C0: C0 = K * V0^T -> fp32 (stride 65: conflict-free solve reads) ----
            f32x4 cacc[2];
            cacc[0] = (f32x4){0.f, 0.f, 0.f, 0.f};
            cacc[1] = (f32x4){0.f, 0.f, 0.f, 0.f};
            prod_cA(kah, kal, V0h_, V0l_, wn, cacc);
#pragma unroll
            for (int j = 0; j < 2; ++j)
#pragma unroll
                for (int rg = 0; rg < 4; ++rg) {
                    const int row = wm * 16 + kg * 4 + rg, col = wn * 32 + j * 16 + m16;
                    C032[row * 65 + col] = cacc[j][rg];
                }
        }
        __syncthreads();   // B3 (C032 visible; V0-LDS dead -> W writable by wave 0)

        // ---- next-chunk global prefetch: issue early, consume after B6 ----
        if (c + 1 < NCHUNK) issue_pf(c + 1);

        f32x4 yacc[2][2];   // custom-tile Y accumulators (waves != 0,4)

        if (wave == 0) {
            // zero the W region (union with V0; safe: V0 consumed before B3)
#pragma unroll
            for (int i0 = 0; i0 < 16; ++i0)
                ((uint4v*)Wh_)[i0 * 64 + lane] = (uint4v){0u, 0u, 0u, 0u};

            // ---- blocked solve: WAVE 0 ONLY, zero internal barriers ----
#pragma unroll
            for (int J = 0; J < 4; ++J) {
                float Nreg[16];
                if (J > 0) {
                    const int lo8 = lane * 8;
#pragma unroll
                    for (int band = 0; band < 4; ++band) {
                        f32x4 acc1 = (f32x4){0.f, 0.f, 0.f, 0.f};
#pragma unroll
                        for (int half = 0; half < 2; ++half) {
                            bf16x8 ah = *(const bf16x8*)&Ah_[(band * 2 + half) * SUBST + lo8];
                            bf16x8 al = *(const bf16x8*)&Al_[(band * 2 + half) * SUBST + lo8];
                            bf16x8 bh = *(const bf16x8*)&Wh_[(J * 2 + half) * SUBST + lo8];
                            bf16x8 bl = *(const bf16x8*)&Wl_[(J * 2 + half) * SUBST + lo8];
                            acc1 = __builtin_amdgcn_mfma_f32_16x16x32_bf16(al, bh, acc1, 0, 0, 0);
                            acc1 = __builtin_amdgcn_mfma_f32_16x16x32_bf16(ah, bl, acc1, 0, 0, 0);
                            acc1 = __builtin_amdgcn_mfma_f32_16x16x32_bf16(ah, bh, acc1, 0, 0, 0);
                        }
#pragma unroll
                        for (int rg = 0; rg < 4; ++rg)
                            N32[(band * 16 + kg * 4 + rg) * 17 + m16] = acc1[rg];
                    }
#pragma unroll
                    for (int j = 0; j < 16; ++j) Nreg[j] = N32[lane * 17 + j];
                }

                float Areg[16], CNreg[16];
                {
                    bf16x8 a0 = *(const bf16x8*)&Ah_[fidx(lane, 16 * J)];
                    bf16x8 a1 = *(const bf16x8*)&Ah_[fidx(lane, 16 * J + 8)];
                    bf16x8 b0 = *(const bf16x8*)&Al_[fidx(lane, 16 * J)];
                    bf16x8 b1 = *(const bf16x8*)&Al_[fidx(lane, 16 * J + 8)];
#pragma unroll
                    for (int e = 0; e < 8; ++e) {
                        Areg[e]     = bf2f((ushort)a0[e]) + bf2f((ushort)b0[e]);
                        Areg[e + 8] = bf2f((ushort)a1[e]) + bf2f((ushort)b1[e]);
                    }
#pragma unroll
                    for (int j = 0; j < 16; ++j) CNreg[j] = C032[lane * 65 + 16 * J + j];
                    if (J > 0) {
#pragma unroll
                        for (int j = 0; j < 16; ++j) CNreg[j] += Nreg[j];
                    }
                }
                float bvreg = bAll[s0 + 16 * J + m16];

                // 16 serial steps; even/odd partial sums halve the FMA chain depth
                float wreg[16];
#pragma unroll
                for (int j = 0; j < 16; ++j) {
                    float sA = CNreg[j], sB = 0.f;
#pragma unroll
                    for (int jj = 0; jj < 16; ++jj) {
                        if (jj < j) {
                            float pr = Areg[jj] * lane_bcast(wreg[jj], 16 * J + j);
                            if (jj & 1) sB += pr; else sA += pr;
                        }
                    }
                    float sum = sA + sB;
                    float beta_s = lane_bcast(bvreg, j);
                    wreg[j] = (lane > 16 * J + j) ? (-beta_s * sum) : 0.f;
                }

                // publish W columns J (octet stores)
                {
                    ushort8 h8[2], l8[2];
#pragma unroll
                    for (int e = 0; e < 16; ++e) {
                        ushort h = f2bf(wreg[e]);
                        h8[e >> 3][e & 7] = h;
                        l8[e >> 3][e & 7] = f2bf(wreg[e] - bf2f(h));
                    }
                    const int o0 = fidx(lane, 16 * J), o1 = fidx(lane, 16 * J + 8);
                    *(ushort8*)&Wh_[o0] = h8[0]; *(ushort8*)&Wh_[o1] = h8[1];
                    *(ushort8*)&Wl_[o0] = l8[0]; *(ushort8*)&Wl_[o1] = l8[1];
                }
            }
        } else {
            // ---- solve-window work: P_YM + P_QK on 6 waves (wave 4 idle so
            //      SIMD0 stays clear for the solver). 8 tiles over waves
            //      {1,2,3,5,6,7}: waves 1,2 take two tiles. ----
            const int nt_w = (wave == 4) ? 0 : ((wave <= 2) ? 2 : 1);
            const int wi = (wave < 4) ? (wave - 1) : (wave - 2);
#pragma unroll
            for (int ti = 0; ti < 2; ++ti) {
                if (ti >= nt_w) continue;
                const int T = (ti == 0) ? wi : (wi + 6);   // wave1:{0,6} wave2:{1,7}
                const int twm = T >> 1, twn = T & 1;
                bf16x8 qh2[2], ql2[2];
                load_af(Qh_, Ql_, twm, qh2, ql2);
                yacc[ti][0] = (f32x4){0.f, 0.f, 0.f, 0.f};
                yacc[ti][1] = (f32x4){0.f, 0.f, 0.f, 0.f};
                if (c > 0) prod_cA(qh2, ql2, MTh_, MTl_, twn, yacc[ti]);   // yacc = Q*M0
                // G = tril_(Q K^T); tiles entirely above the diagonal skip the product
                const bool gz = (twm * 16 + 15) <= (twn * 32);
                f32x4 ga[2];
                ga[0] = (f32x4){0.f, 0.f, 0.f, 0.f};
                ga[1] = (f32x4){0.f, 0.f, 0.f, 0.f};
                if (!gz) prod_cA(qh2, ql2, Kh_, Kl_, twn, ga);
#pragma unroll
                for (int j = 0; j < 2; ++j)
#pragma unroll
                    for (int rg = 0; rg < 4; ++rg) {
                        const int row = twm * 16 + kg * 4 + rg, col = twn * 32 + j * 16 + m16;
                        const float gv = (row > col) ? ga[j][rg] : 0.f;
                        const ushort h = f2bf(gv);
                        const int ii = fidx(row, col);
                        Gh_[ii] = h; Gl_[ii] = f2bf(gv - bf2f(h));
                    }
            }
        }
        __syncthreads();   // B4 (full W + G visible)

        {
            // ---- P_Delta: Delta = V0(reg) + W * K ; write DT = (beta Delta)^T ----
            f32x4 dacc[2];
            dacc[0] = V0acc[0]; dacc[1] = V0acc[1];
            bf16x8 wh2[2], wl2[2];
            load_af(Wh_, Wl_, wm, wh2, wl2);
            prod_cA(wh2, wl2, KTh_, KTl_, wn, dacc);
#pragma unroll
            for (int j = 0; j < 2; ++j)
#pragma unroll
                for (int rg = 0; rg < 4; ++rg) {
                    const int row = wm * 16 + kg * 4 + rg, col = wn * 32 + j * 16 + m16;
                    const float dv = dacc[j][rg] * bAll[s0 + row];   // beta_s * delta_s[d]
                    const ushort h = f2bf(dv);
                    const int ii = fidx(col, row);                   // DT[d][s]
                    DTh_[ii] = h; DTl_[ii] = f2bf(dv - bf2f(h));
                }
        }
        __syncthreads();   // B5 (DT ready)

        // ---- P_Y2: Y = yacc + G * DT^T -> global (custom tile map) ----
        if (wave != 0) {
            const int nt_w = (wave == 4) ? 0 : ((wave <= 2) ? 2 : 1);
            const int wi = (wave < 4) ? (wave - 1) : (wave - 2);
#pragma unroll
            for (int ti = 0; ti < 2; ++ti) {
                if (ti >= nt_w) continue;
                const int T = (ti == 0) ? wi : (wi + 6);
                const int twm = T >> 1, twn = T & 1;
                bf16x8 gh2[2], gl2[2];
                load_af(Gh_, Gl_, twm, gh2, gl2);
                prod_cA(gh2, gl2, DTh_, DTl_, twn, yacc[ti]);
#pragma unroll
                for (int j = 0; j < 2; ++j)
#pragma unroll
                    for (int rg = 0; rg < 4; ++rg) {
                        const int row = twm * 16 + kg * 4 + rg, col = twn * 32 + j * 16 + m16;
                        Yg[(size_t)(bS + s0 + row) * D_MODEL + nOff + col] = yacc[ti][j][rg];
                    }
            }
        }
        {
            // ---- P_M: Macc += K^T (beta Delta); state writeback (M + transposed MT) ----
            bf16x8 kth[2], ktl[2];
            load_af(KTh_, KTl_, wm, kth, ktl);
            prod_cA(kth, ktl, DTh_, DTl_, wn, Macc);
            if (c < NCHUNK - 1) {
#pragma unroll
                for (int j = 0; j < 2; ++j)
#pragma unroll
                    for (int rg = 0; rg < 4; ++rg) {
                        const int row = wm * 16 + kg * 4 + rg, col = wn * 32 + j * 16 + m16;
                        const float mv = Macc[j][rg];
                        const ushort h = f2bf(mv), l = f2bf(mv - bf2f(h));
                        const int ii = fidx(row, col);
                        Mh_[ii] = h; Ml_[ii] = l;
                        const int iT = fidx(col, row);   // MT = M^T, same fp32 value
                        MTh_[iT] = h; MTl_[iT] = l;
                    }
            }
        }
        __syncthreads();   // B6 (state + unions settled for next chunk)
    }
}

// ---------------------------------------------------------------------------
// RMSNorm. SPLIT=1: write fp16 for final GEMM. SPLIT=0: fp32 in place.
// ---------------------------------------------------------------------------
template <int SPLIT>
__global__ __launch_bounds__(256) void rmsnorm_kernel(float* __restrict__ Y,
                                                      const float* __restrict__ w,
                                                      unsigned short* __restrict__ H) {
    __shared__ float red[4];
    float* y = Y + (size_t)blockIdx.x * D_MODEL;
    const int t = threadIdx.x;
    const int wv = t >> 6, ln = t & 63;
    float4 v = ((float4*)y)[t];
    float ss = v.x * v.x + v.y * v.y + v.z * v.z + v.w * v.w;
#pragma unroll
    for (int off = 32; off; off >>= 1) ss += __shfl_xor(ss, off);
    if (ln == 0) red[wv] = ss;
    __syncthreads();
    float tot = red[0] + red[1] + red[2] + red[3];
    float inv = 1.f / sqrtf(tot * (1.f / D_MODEL) + 1e-6f);
    const float4 wv4 = ((const float4*)w)[t];
    v.x *= inv * wv4.x; v.y *= inv * wv4.y;
    v.z *= inv * wv4.z; v.w *= inv * wv4.w;
    if (SPLIT) {
        us4 h;
        h.x = f2h(v.x); h.y = f2h(v.y); h.z = f2h(v.z); h.w = f2h(v.w);
        size_t i = (size_t)blockIdx.x * 256 + t;
        ((us4*)H)[i] = h;
    } else {
        ((float4*)y)[t] = v;
    }
}

// ---------------------------------------------------------------------------
extern "C" void kernel_launch(void* const* d_in, const int* in_sizes, int n_in,
                              void* d_out, int out_size, void* d_ws, size_t ws_size,
                              hipStream_t stream) {
    const float* x     = (const float*)d_in[0];
    const float* Wq    = (const float*)d_in[1];
    const float* Wk    = (const float*)d_in[2];
    const float* Wv    = (const float*)d_in[3];
    const float* Wb    = (const float*)d_in[4];
    const float* Wo    = (const float*)d_in[5];
    const float* rms_w = (const float*)d_in[6];
    float* out = (float*)d_out;

    char* p = (char*)d_ws;
    float* Q  = (float*)p;  p += (size_t)RD * 4;
    float* Kp = (float*)p;  p += (size_t)RD * 4;
    float* Vp = (float*)p;  p += (size_t)RD * 4;
    float* Y  = (float*)p;  p += (size_t)RD * 4;
    float* Bt = (float*)p;  p += (size_t)32768 * 4;
    unsigned short* xh  = (unsigned short*)p;  p += (size_t)RD * 2;   // fp16; reused as Yh
    unsigned short* xl  = (unsigned short*)p;  p += (size_t)RD * 2;   // unused in fast path
    unsigned short* Wsh = (unsigned short*)p;  p += (size_t)WSZ * 2;
    unsigned short* Wsl = (unsigned short*)p;  p += (size_t)WSZ * 2;  // holds Wo-fp16
    const size_t need_fast = (size_t)RD * 16 + 131072 + (size_t)RD * 4 + (size_t)WSZ * 4;
    const bool fast = ws_size >= need_fast;

    // Wk/Wv fp16 conversions parked in Y (dead until scan writes it);
    // Wo-fp16 parked in Wsl (never otherwise touched in fast path).
    unsigned short* Wkh = (unsigned short*)Y;
    unsigned short* Wvh = Wkh + WSZ;
    unsigned short* Woh = Wsl;

    (void)hipFuncSetAttribute(reinterpret_cast<const void*>(scan_chunked),
                              hipFuncAttributeMaxDynamicSharedMemorySize, SMEM_SCAN);

    if (fast) {
        dim3 ggrid(D_MODEL / 128, ROWS / 128);      // (8,16) = 128 blocks
        dim3 qgrid(D_MODEL / 128, ROWS / 128, 3);   // 384 blocks = 1.5/CU
        split_kernel<<<RD / 4 / 256, 256, 0, stream>>>(x, xh, RD / 4);
        split4_kernel<<<WSZ / 256, 256, 0, stream>>>(Wq, Wk, Wv, Wo,
                                                     Wsh, Wkh, Wvh, Woh);
        gemm_qkv<<<qgrid, 256, 0, stream>>>(xh, Wsh, Wkh, Wvh, Q, Kp, Vp);
        beta_kernel<<<ROWS / 4, 256, 0, stream>>>(x, Wb, Bt);
        scan_chunked<<<BATCH * NHEAD, 512, SMEM_SCAN, stream>>>(Q, Kp, Vp, Bt, Y);
        rmsnorm_kernel<1><<<ROWS, 256, 0, stream>>>(Y, rms_w, xh);
        gemm_f16s<0><<<ggrid, 256, 0, stream>>>(xh, Woh, out, ROWS, D_MODEL, D_MODEL);
    } else {
        dim3 ggrid(D_MODEL / 128, ROWS / 128);  // (8,16)
        gemm_mfma<1><<<ggrid, 256, 0, stream>>>(x, Wq, Q, ROWS, D_MODEL, D_MODEL);
        gemm_mfma<1><<<ggrid, 256, 0, stream>>>(x, Wk, Kp, ROWS, D_MODEL, D_MODEL);
        gemm_mfma<1><<<ggrid, 256, 0, stream>>>(x, Wv, Vp, ROWS, D_MODEL, D_MODEL);
        beta_kernel<<<ROWS / 4, 256, 0, stream>>>(x, Wb, Bt);
        norm_qk<<<2 * ROWS * NHEAD / 4, 256, 0, stream>>>(Q, Kp);
        scan_chunked<<<BATCH * NHEAD, 512, SMEM_SCAN, stream>>>(Q, Kp, Vp, Bt, Y);
        rmsnorm_kernel<0><<<ROWS, 256, 0, stream>>>(Y, rms_w, nullptr);
        gemm_mfma<0><<<ggrid, 256, 0, stream>>>(Y, Wo, out, ROWS, D_MODEL, D_MODEL);
    }
}

// Round 10
// 375.592 us; speedup vs baseline: 1.0142x; 1.0142x over previous
//
#include <hip/hip_runtime.h>
#include <math.h>

#define D_MODEL 1024
#define NHEAD 16
#define HEAD_DIM 64
#define BATCH 2
#define SEQ 1024
#define ROWS (BATCH * SEQ)        // 2048
#define RD (ROWS * D_MODEL)       // 2097152
#define WSZ (D_MODEL * D_MODEL)   // 1048576
#define CHUNK 64
#define NCHUNK (SEQ / CHUNK)      // 16

typedef __attribute__((ext_vector_type(8))) short bf16x8;
typedef __attribute__((ext_vector_type(8))) _Float16 f16x8;
typedef __attribute__((ext_vector_type(8))) unsigned short ushort8;
typedef __attribute__((ext_vector_type(4))) unsigned short us4;
typedef __attribute__((ext_vector_type(4))) float f32x4;
typedef __attribute__((ext_vector_type(4))) unsigned int uint4v;
typedef unsigned short ushort;

// ---------------------------------------------------------------------------
// helpers
// ---------------------------------------------------------------------------
__device__ __forceinline__ void load_lds_16u(const unsigned short* g, unsigned short* l) {
    __builtin_amdgcn_global_load_lds((const __attribute__((address_space(1))) void*)g,
                                     (__attribute__((address_space(3))) void*)l, 16, 0, 0);
}
// fp32 -> bf16 RNE, and back (scan-internal precision scheme + fallback GEMM)
__device__ __forceinline__ unsigned short f2bf(float x) {
    unsigned int u = __float_as_uint(x);
    unsigned int r = (u + 0x7FFFu + ((u >> 16) & 1u)) >> 16;
    return (unsigned short)r;
}
__device__ __forceinline__ float bf2f(unsigned short h) {
    return __uint_as_float(((unsigned int)h) << 16);
}
// fp32 -> fp16 RNE (GEMM path)
__device__ __forceinline__ unsigned short f2h(float x) {
    _Float16 h = (_Float16)x;
    return __builtin_bit_cast(unsigned short, h);
}
// uniform-lane broadcast (SALU path, not LDS)
__device__ __forceinline__ float lane_bcast(float v, int lane) {
    return __uint_as_float(__builtin_amdgcn_readlane(__float_as_uint(v), lane));
}
// fragment-order index (SUBST=512 validated; no swizzle — R4 showed swizzle
// cuts conflicts but regresses time on the latency-critical chain)
#define SUBST 512
#define FBUF (8 * SUBST * 2)   // 8192 bytes per 64x64 operand buffer
__device__ __forceinline__ int fidx(int r, int k) {
    return ((r >> 4) * 2 + (k >> 5)) * SUBST + ((((k & 31) >> 3) << 4) + (r & 15)) * 8 + (k & 7);
}

// ---------------------------------------------------------------------------
// R10 = R8 verbatim (best validated: 377.8 µs). R9's 128x128 GEMM tiles were
// neutral-to-negative (staging savings offset by occupancy 3->1.5 blocks/CU);
// reverted. Session summary of validated deltas vs the 445 µs start:
//   R5: GEMM path dual-bf16 3-product -> fp16 single-product  (-55 µs)
//   R8: q/k L2-norm fused into gemm_qkv epilogue + split4      (-10 µs)
// Scan is v6 (latency-bound, 32 blocks / 1 per CU): 4 structural attempts
// (16-wave, XOR swizzle, fp16 scheme x2) all failed or regressed — frozen.
// ---------------------------------------------------------------------------

// split: fp32 -> fp16 buffer. n4 = n/4 float4 groups.
__global__ __launch_bounds__(256) void split_kernel(const float* __restrict__ X,
                                                    unsigned short* __restrict__ H,
                                                    int n4) {
    int i = blockIdx.x * 256 + threadIdx.x;
    if (i >= n4) return;
    float4 v = ((const float4*)X)[i];
    us4 h;
    h.x = f2h(v.x); h.y = f2h(v.y); h.z = f2h(v.z); h.w = f2h(v.w);
    ((us4*)H)[i] = h;
}

// fused 4-way weight convert (one launch for Wq, Wk, Wv, Wo)
__global__ __launch_bounds__(256) void split4_kernel(const float* __restrict__ W0,
                                                     const float* __restrict__ W1,
                                                     const float* __restrict__ W2,
                                                     const float* __restrict__ W3,
                                                     unsigned short* __restrict__ H0,
                                                     unsigned short* __restrict__ H1,
                                                     unsigned short* __restrict__ H2,
                                                     unsigned short* __restrict__ H3) {
    const int n4 = WSZ / 4;
    int i = blockIdx.x * 256 + threadIdx.x;
    const int which = i / n4;
    const int j = i - which * n4;
    const float* X = (which == 0) ? W0 : (which == 1) ? W1 : (which == 2) ? W2 : W3;
    unsigned short* H = (which == 0) ? H0 : (which == 1) ? H1 : (which == 2) ? H2 : H3;
    float4 v = ((const float4*)X)[j];
    us4 h;
    h.x = f2h(v.x); h.y = f2h(v.y); h.z = f2h(v.z); h.w = f2h(v.w);
    ((us4*)H)[j] = h;
}

// ---------------------------------------------------------------------------
// GEMM core, fp16 single-product (R5-validated). 256 threads / 4 waves; tile
// 128x64. Optional fused per-row L2 norm over the 64-col tile (= one head).
// ---------------------------------------------------------------------------
template <int ACT>
__device__ __forceinline__ void gemm_core_f16(const unsigned short* __restrict__ Ah,
                                              const unsigned short* __restrict__ Bh,
                                              float* __restrict__ C,
                                              int M, int N, int K,
                                              unsigned short* LA0, unsigned short* LB0,
                                              float* NP, bool do_norm) {
    const int t = threadIdx.x;
    const int wave = t >> 6, lane = t & 63;
    const int wm = wave >> 1, wn = wave & 1;
    const int m16 = lane & 15, kg = lane >> 4;
    const int row0 = blockIdx.y * 128, col0 = blockIdx.x * 64;

    f32x4 acc[4][2];
#pragma unroll
    for (int i = 0; i < 4; ++i)
#pragma unroll
        for (int j = 0; j < 2; ++j) acc[i][j] = (f32x4){0.f, 0.f, 0.f, 0.f};

    for (int k0 = 0; k0 < K; k0 += 32) {
#pragma unroll
        for (int ci = 0; ci < 3; ++ci) {
            const int c = wave * 3 + ci;   // 0..11
            const unsigned short* src;
            unsigned short* dst;
            int g16, rbase;
            if (c < 8) { src = Ah; dst = &LA0[c * 512];       g16 = c;     rbase = row0; }
            else       { src = Bh; dst = &LB0[(c - 8) * 512]; g16 = c - 8; rbase = col0; }
            const unsigned short* gp = src + (size_t)(rbase + g16 * 16 + m16) * K + k0 + kg * 8;
            load_lds_16u(gp, dst);
        }
        __syncthreads();

        f16x8 fah[4], fbh[2];
#pragma unroll
        for (int mt = 0; mt < 4; ++mt)
            fah[mt] = *(const f16x8*)&LA0[(wm * 4 + mt) * 512 + lane * 8];
#pragma unroll
        for (int nt = 0; nt < 2; ++nt)
            fbh[nt] = *(const f16x8*)&LB0[(wn * 2 + nt) * 512 + lane * 8];
#pragma unroll
        for (int mt = 0; mt < 4; ++mt)
#pragma unroll
            for (int nt = 0; nt < 2; ++nt)
                acc[mt][nt] = __builtin_amdgcn_mfma_f32_16x16x32_f16(fah[mt], fbh[nt], acc[mt][nt], 0, 0, 0);
        __syncthreads();
    }

    // epilogue: activation -> (optional) per-row L2 norm over the 64-col tile
    float sv[4][2][4];
#pragma unroll
    for (int mt = 0; mt < 4; ++mt)
#pragma unroll
        for (int nt = 0; nt < 2; ++nt)
#pragma unroll
            for (int rg = 0; rg < 4; ++rg) {
                float v = acc[mt][nt][rg];
                if (ACT == 1) v = v / (1.f + expf(-v));
                sv[mt][nt][rg] = v;
            }
    if (do_norm) {
        // row = wm*64 + mt*16 + kg*4 + rg; cols split as wn*32 + nt*16 + m16.
        // Per-thread partial over 2 cols -> 16-lane m16-group butterfly ->
        // cross-wave (wn) combine in NP[2][128].
#pragma unroll
        for (int mt = 0; mt < 4; ++mt)
#pragma unroll
            for (int rg = 0; rg < 4; ++rg) {
                float ss = sv[mt][0][rg] * sv[mt][0][rg] + sv[mt][1][rg] * sv[mt][1][rg];
#pragma unroll
                for (int off = 8; off; off >>= 1) ss += __shfl_xor(ss, off);
                if (m16 == 0) NP[wn * 128 + wm * 64 + mt * 16 + kg * 4 + rg] = ss;
            }
        __syncthreads();
#pragma unroll
        for (int mt = 0; mt < 4; ++mt)
#pragma unroll
            for (int rg = 0; rg < 4; ++rg) {
                const int rw = wm * 64 + mt * 16 + kg * 4 + rg;
                const float inv = 1.f / (sqrtf(NP[rw] + NP[128 + rw]) + 1e-6f);
                sv[mt][0][rg] *= inv;
                sv[mt][1][rg] *= inv;
            }
    }
#pragma unroll
    for (int mt = 0; mt < 4; ++mt)
#pragma unroll
        for (int nt = 0; nt < 2; ++nt) {
            const int rowb = row0 + wm * 64 + mt * 16 + kg * 4;
            const int col  = col0 + wn * 32 + nt * 16 + m16;
#pragma unroll
            for (int rg = 0; rg < 4; ++rg)
                C[(size_t)(rowb + rg) * N + col] = sv[mt][nt][rg];
        }
}

template <int ACT>
__global__ __launch_bounds__(256) void gemm_f16s(const unsigned short* __restrict__ Ah,
                                                 const unsigned short* __restrict__ Bh,
                                                 float* __restrict__ C,
                                                 int M, int N, int K) {
    __shared__ unsigned short LA[8 * 512];
    __shared__ unsigned short LB[4 * 512];
    gemm_core_f16<ACT>(Ah, Bh, C, M, N, K, LA, LB, nullptr, false);
}

// fused QKV GEMM: blockIdx.z selects weight/output; q/k rows L2-normalized
// in the epilogue (each 64-col tile = one head).
__global__ __launch_bounds__(256) void gemm_qkv(const unsigned short* __restrict__ Ah,
                                                const unsigned short* __restrict__ Bqh,
                                                const unsigned short* __restrict__ Bkh,
                                                const unsigned short* __restrict__ Bvh,
                                                float* __restrict__ Cq,
                                                float* __restrict__ Ck,
                                                float* __restrict__ Cv) {
    __shared__ unsigned short LA[8 * 512];
    __shared__ unsigned short LB[4 * 512];
    __shared__ float NP[2 * 128];
    const int z = blockIdx.z;
    const unsigned short* Bh = (z == 0) ? Bqh : (z == 1) ? Bkh : Bvh;
    float* C = (z == 0) ? Cq : (z == 1) ? Ck : Cv;
    gemm_core_f16<1>(Ah, Bh, C, ROWS, D_MODEL, D_MODEL, LA, LB, NP, z < 2);
}

// ---------------------------------------------------------------------------
// Fallback GEMM (inline bf16 split) — only if ws_size too small. Unchanged.
// ---------------------------------------------------------------------------
#define LDST 40
template <int ACT>
__global__ __launch_bounds__(256) void gemm_mfma(const float* __restrict__ A,
                                                 const float* __restrict__ B,
                                                 float* __restrict__ C,
                                                 int M, int N, int K) {
    __shared__ unsigned short Ahi[128 * LDST], Alo[128 * LDST];
    __shared__ unsigned short Bhi[128 * LDST], Blo[128 * LDST];

    const int t = threadIdx.x;
    const int wave = t >> 6, lane = t & 63;
    const int wm = wave >> 1, wn = wave & 1;
    const int row0 = blockIdx.y * 128, col0 = blockIdx.x * 128;
    const int sr = t >> 1;
    const int sh = t & 1;
    const int m16 = lane & 15, kg = lane >> 4;

    f32x4 acc[4][4];
#pragma unroll
    for (int i = 0; i < 4; ++i)
#pragma unroll
        for (int j = 0; j < 4; ++j) acc[i][j] = (f32x4){0.f, 0.f, 0.f, 0.f};

    const float* ga = A + (size_t)(row0 + sr) * K + sh * 16;
    const float* gb = B + (size_t)(col0 + sr) * K + sh * 16;
    const int sbase = sr * LDST + sh * 16;

    for (int k0 = 0; k0 < K; k0 += 32) {
        float af[16], bf[16];
#pragma unroll
        for (int i = 0; i < 4; ++i) {
            float4 a4 = *(const float4*)(ga + k0 + i * 4);
            float4 b4 = *(const float4*)(gb + k0 + i * 4);
            af[i * 4 + 0] = a4.x; af[i * 4 + 1] = a4.y; af[i * 4 + 2] = a4.z; af[i * 4 + 3] = a4.w;
            bf[i * 4 + 0] = b4.x; bf[i * 4 + 1] = b4.y; bf[i * 4 + 2] = b4.z; bf[i * 4 + 3] = b4.w;
        }
        ushort8 ah0, ah1, al0, al1, bh0, bh1, bl0, bl1;
#pragma unroll
        for (int j = 0; j < 8; ++j) {
            unsigned short h = f2bf(af[j]);       ah0[j] = h; al0[j] = f2bf(af[j] - bf2f(h));
            h = f2bf(af[j + 8]);                  ah1[j] = h; al1[j] = f2bf(af[j + 8] - bf2f(h));
            h = f2bf(bf[j]);                      bh0[j] = h; bl0[j] = f2bf(bf[j] - bf2f(h));
            h = f2bf(bf[j + 8]);                  bh1[j] = h; bl1[j] = f2bf(bf[j + 8] - bf2f(h));
        }
        *(ushort8*)&Ahi[sbase] = ah0;  *(ushort8*)&Ahi[sbase + 8] = ah1;
        *(ushort8*)&Alo[sbase] = al0;  *(ushort8*)&Alo[sbase + 8] = al1;
        *(ushort8*)&Bhi[sbase] = bh0;  *(ushort8*)&Bhi[sbase + 8] = bh1;
        *(ushort8*)&Blo[sbase] = bl0;  *(ushort8*)&Blo[sbase + 8] = bl1;
        __syncthreads();

        bf16x8 fah[4], fal[4], fbh[4], fbl[4];
#pragma unroll
        for (int i = 0; i < 4; ++i) {
            const int ar = (wm * 64 + i * 16 + m16) * LDST + kg * 8;
            const int br = (wn * 64 + i * 16 + m16) * LDST + kg * 8;
            fah[i] = *(const bf16x8*)&Ahi[ar];
            fal[i] = *(const bf16x8*)&Alo[ar];
            fbh[i] = *(const bf16x8*)&Bhi[br];
            fbl[i] = *(const bf16x8*)&Blo[br];
        }
#pragma unroll
        for (int i = 0; i < 4; ++i)
#pragma unroll
            for (int j = 0; j < 4; ++j) {
                acc[i][j] = __builtin_amdgcn_mfma_f32_16x16x32_bf16(fal[i], fbh[j], acc[i][j], 0, 0, 0);
                acc[i][j] = __builtin_amdgcn_mfma_f32_16x16x32_bf16(fah[i], fbl[j], acc[i][j], 0, 0, 0);
                acc[i][j] = __builtin_amdgcn_mfma_f32_16x16x32_bf16(fah[i], fbh[j], acc[i][j], 0, 0, 0);
            }
        __syncthreads();
    }

#pragma unroll
    for (int i = 0; i < 4; ++i)
#pragma unroll
        for (int j = 0; j < 4; ++j) {
            const int col = col0 + wn * 64 + j * 16 + m16;
            const int rowb = row0 + wm * 64 + i * 16 + kg * 4;
#pragma unroll
            for (int rg = 0; rg < 4; ++rg) {
                float v = acc[i][j][rg];
                if (ACT == 1) v = v / (1.f + expf(-v));
                C[(size_t)(rowb + rg) * N + col] = v;
            }
        }
}

// ---------------------------------------------------------------------------
// beta = 2*sigmoid(x @ Wb^T)  : (ROWS, NHEAD). One wave per row. (fp32)
// ---------------------------------------------------------------------------
__global__ __launch_bounds__(256) void beta_kernel(const float* __restrict__ x,
                                                   const float* __restrict__ Wb,
                                                   float* __restrict__ beta) {
    const int wave = blockIdx.x * 4 + (threadIdx.x >> 6);
    const int lane = threadIdx.x & 63;
    const float* xr = x + (size_t)wave * D_MODEL;
    float xv[16];
#pragma unroll
    for (int j = 0; j < 16; ++j) xv[j] = xr[lane + 64 * j];
    for (int n = 0; n < NHEAD; ++n) {
        const float* wr = Wb + (size_t)n * D_MODEL;
        float s = 0.f;
#pragma unroll
        for (int j = 0; j < 16; ++j) s += xv[j] * wr[lane + 64 * j];
#pragma unroll
        for (int off = 32; off; off >>= 1) s += __shfl_xor(s, off);
        if (lane == 0) beta[(size_t)wave * NHEAD + n] = 2.f / (1.f + expf(-s));
    }
}

// ---------------------------------------------------------------------------
// L2-normalize q and k per (row, head) over HEAD_DIM=64. (fallback path only)
// ---------------------------------------------------------------------------
__global__ __launch_bounds__(256) void norm_qk(float* __restrict__ Q,
                                               float* __restrict__ Kp) {
    const int TOT = ROWS * NHEAD;
    int wave = blockIdx.x * 4 + (threadIdx.x >> 6);
    const int lane = threadIdx.x & 63;
    float* T = (wave < TOT) ? Q : Kp;
    int w = (wave < TOT) ? wave : wave - TOT;
    float* p = T + (size_t)(w >> 4) * D_MODEL + (size_t)(w & 15) * HEAD_DIM;
    float v = p[lane];
    float ss = v * v;
#pragma unroll
    for (int off = 32; off; off >>= 1) ss += __shfl_xor(ss, off);
    p[lane] = v / (sqrtf(ss) + 1e-6f);
}

// ---------------------------------------------------------------------------
// Chunked delta-rule scan v6 — VALIDATED at 214.8-215.5 µs (R1/R5/R8), verbatim.
// R4's XOR swizzle cut bank conflicts 34% but regressed +9% (latency-bound).
// R6/R7's fp16 scheme NaN'd twice (cause not localizable). Do not touch.
//   Hazard audit (6 barriers/chunk):
//     V0/W union: V0 wr B1-B2, rd B2-B3; W zero+wr B3-B4 (wave0), rd B4-B5.
//     K/DT union: K wr stage, rd through B3-B4 (window QK); DT wr B4-B5,
//                 rd B5-B6.  Q: wr stage, rd B3-B4.  G: wr B3-B4, rd B5-B6.
//     M/MT: wr B5-B6, rd next chunk B1-B4.  C032: wr B2-B3, rd B3-B4.
// ---------------------------------------------------------------------------
#define SMEM_SCAN 156160   // 14*FBUF + 16640(C032) + 2*FBUF(A) + 4352(N32) + 4096(bAll)

__global__ __launch_bounds__(512, 1) void scan_chunked(const float* __restrict__ Qg,
                                                       const float* __restrict__ Kg,
                                                       const float* __restrict__ Vg,
                                                       const float* __restrict__ Btg,
                                                       float* __restrict__ Yg) {
    extern __shared__ char smem[];
    ushort* Mh_  = (ushort*)(smem + 0 * FBUF);
    ushort* Ml_  = (ushort*)(smem + 1 * FBUF);
    ushort* MTh_ = (ushort*)(smem + 2 * FBUF);
    ushort* MTl_ = (ushort*)(smem + 3 * FBUF);
    ushort* KTh_ = (ushort*)(smem + 4 * FBUF);
    ushort* KTl_ = (ushort*)(smem + 5 * FBUF);
    ushort* V0h_ = (ushort*)(smem + 6 * FBUF);   // union1: V0 / W
    ushort* V0l_ = (ushort*)(smem + 7 * FBUF);
    ushort* Wh_  = V0h_;
    ushort* Wl_  = V0l_;
    ushort* Gh_  = (ushort*)(smem + 8 * FBUF);
    ushort* Gl_  = (ushort*)(smem + 9 * FBUF);
    ushort* Kh_  = (ushort*)(smem + 10 * FBUF);  // union2: K / DT
    ushort* Kl_  = (ushort*)(smem + 11 * FBUF);
    ushort* DTh_ = Kh_;
    ushort* DTl_ = Kl_;
    ushort* Qh_  = (ushort*)(smem + 12 * FBUF);  // standalone
    ushort* Ql_  = (ushort*)(smem + 13 * FBUF);
    float*  C032 = (float*)(smem + 14 * FBUF);                     // 64x65 fp32 (16640 B)
    ushort* Ah_  = (ushort*)(smem + 14 * FBUF + 16640);
    ushort* Al_  = (ushort*)(smem + 15 * FBUF + 16640);
    float*  N32  = (float*)(smem + 16 * FBUF + 16640);             // 64x17 fp32 (4352 B)
    float*  bAll = (float*)(smem + 16 * FBUF + 16640 + 4352);      // 1024 fp32 (4096 B)

    const int b = blockIdx.x >> 4;
    const int n = blockIdx.x & 15;
    const int t = threadIdx.x;
    const int wave = t >> 6, lane = t & 63;
    const int wm = wave >> 1, wn = wave & 1;      // 4x2 wave grid (std tiling)
    const int m16 = lane & 15, kg = lane >> 4;
    const int bS = b * SEQ;
    const int nOff = n * HEAD_DIM;
    const int r = t >> 3, g = t & 7;   // staging: row r (0..63), col-octet g (0..7)

    // fp32 register state: row = wm*16 + kg*4 + rg, col = wn*32 + j*16 + m16
    f32x4 Macc[2];
    Macc[0] = (f32x4){0.f, 0.f, 0.f, 0.f};
    Macc[1] = (f32x4){0.f, 0.f, 0.f, 0.f};

    // ---- helpers ----
    auto load_af = [&](const ushort* Xh, const ushort* Xl, int tm, bf16x8* oh, bf16x8* ol) {
        const int lo8 = lane * 8;
#pragma unroll
        for (int half = 0; half < 2; ++half) {
            oh[half] = *(const bf16x8*)&Xh[(tm * 2 + half) * SUBST + lo8];
            ol[half] = *(const bf16x8*)&Xl[(tm * 2 + half) * SUBST + lo8];
        }
    };
    auto prod_cA = [&](const bf16x8* ah, const bf16x8* al,
                       const ushort* Bh, const ushort* Bl, int tn, f32x4* acc) {
        const int lo8 = lane * 8;
#pragma unroll
        for (int half = 0; half < 2; ++half) {
#pragma unroll
            for (int j = 0; j < 2; ++j) {
                const int jg = tn * 2 + j;
                bf16x8 bh = *(const bf16x8*)&Bh[(jg * 2 + half) * SUBST + lo8];
                bf16x8 bl = *(const bf16x8*)&Bl[(jg * 2 + half) * SUBST + lo8];
                acc[j] = __builtin_amdgcn_mfma_f32_16x16x32_bf16(al[half], bh, acc[j], 0, 0, 0);
                acc[j] = __builtin_amdgcn_mfma_f32_16x16x32_bf16(ah[half], bl, acc[j], 0, 0, 0);
                acc[j] = __builtin_amdgcn_mfma_f32_16x16x32_bf16(ah[half], bh, acc[j], 0, 0, 0);
            }
        }
    };

    // ---- one-time beta preload ----
    for (int i = t; i < SEQ; i += 512) bAll[i] = Btg[(size_t)(bS + i) * NHEAD + n];

    // ---- global prefetch registers (K,Q row-octets; V in std-tile layout) ----
    float4 pk0, pk1, pq0, pq1;
    float pv[8];
    auto issue_pf = [&](int cc) {
        const int so = cc * CHUNK;
        const float* gK = Kg + (size_t)(bS + so + r) * D_MODEL + nOff + g * 8;
        const float* gQ = Qg + (size_t)(bS + so + r) * D_MODEL + nOff + g * 8;
        pk0 = ((const float4*)gK)[0]; pk1 = ((const float4*)gK)[1];
        pq0 = ((const float4*)gQ)[0]; pq1 = ((const float4*)gQ)[1];
        const float* gV = Vg + (size_t)(bS + so) * D_MODEL + nOff;
#pragma unroll
        for (int j = 0; j < 2; ++j)
#pragma unroll
            for (int rg = 0; rg < 4; ++rg)
                pv[j * 4 + rg] = gV[(size_t)(wm * 16 + kg * 4 + rg) * D_MODEL + wn * 32 + j * 16 + m16];
    };
    issue_pf(0);

    for (int c = 0; c < NCHUNK; ++c) {
        const int s0 = c * CHUNK;

        // ---- stage K (+transpose), Q from prefetch regs ----
        {
            float kf[8] = {pk0.x, pk0.y, pk0.z, pk0.w, pk1.x, pk1.y, pk1.z, pk1.w};
            float qf[8] = {pq0.x, pq0.y, pq0.z, pq0.w, pq1.x, pq1.y, pq1.z, pq1.w};
            ushort8 kh8, kl8, qh8, ql8;
            ushort khv[8], klv[8];
#pragma unroll
            for (int e = 0; e < 8; ++e) {
                ushort h = f2bf(kf[e]);
                ushort l = f2bf(kf[e] - bf2f(h));
                khv[e] = h; klv[e] = l;
                kh8[e] = h; kl8[e] = l;
                h = f2bf(qf[e]); l = f2bf(qf[e] - bf2f(h));
                qh8[e] = h; ql8[e] = l;
            }
            const int o0 = fidx(r, g * 8);
            *(ushort8*)&Kh_[o0] = kh8;
            *(ushort8*)&Kl_[o0] = kl8;
            *(ushort8*)&Qh_[o0] = qh8;
            *(ushort8*)&Ql_[o0] = ql8;
#pragma unroll
            for (int e = 0; e < 8; ++e) {
                const int ib = fidx(g * 8 + e, r);
                KTh_[ib] = khv[e]; KTl_[ib] = klv[e];
            }
        }
        __syncthreads();   // B1

        bf16x8 kah[2], kal[2];     // cached K A-frags: live through P_C0
        f32x4 V0acc[2];
        {
            load_af(Kh_, Kl_, wm, kah, kal);
            // ---- P_R: V0 = V(reg) - K*M0^T ----
            V0acc[0] = (f32x4){0.f, 0.f, 0.f, 0.f};
            V0acc[1] = (f32x4){0.f, 0.f, 0.f, 0.f};
            if (c > 0) prod_cA(kah, kal, Mh_, Ml_, wn, V0acc);
#pragma unroll
            for (int j = 0; j < 2; ++j)
#pragma unroll
                for (int rg = 0; rg < 4; ++rg)
                    V0acc[j][rg] = pv[j * 4 + rg] - V0acc[j][rg];
            // V0 -> LDS (W-union buffer; wave 0 overwrites only after B3)
#pragma unroll
            for (int j = 0; j < 2; ++j)
#pragma unroll
                for (int rg = 0; rg < 4; ++rg) {
                    const int row = wm * 16 + kg * 4 + rg, col = wn * 32 + j * 16 + m16;
                    const float v0 = V0acc[j][rg];
                    const ushort h = f2bf(v0);
                    const int ii = fidx(row, col);
                    V0h_[ii] = h; V0l_[ii] = f2bf(v0 - bf2f(h));
                }
            // ---- P_A: A = K K^T (A-frags cached) ----
            f32x4 aacc[2];
            aacc[0] = (f32x4){0.f, 0.f, 0.f, 0.f};
            aacc[1] = (f32x4){0.f, 0.f, 0.f, 0.f};
            prod_cA(kah, kal, Kh_, Kl_, wn, aacc);
#pragma unroll
            for (int j = 0; j < 2; ++j)
#pragma unroll
                for (int rg = 0; rg < 4; ++rg) {
                    const int row = wm * 16 + kg * 4 + rg, col = wn * 32 + j * 16 + m16;
                    const float av = aacc[j][rg];
                    const ushort h = f2bf(av);
                    const int ii = fidx(row, col);
                    Ah_[ii] = h; Al_[ii] = f2bf(av - bf2f(h));
                }
        }
        __syncthreads();   // B2 (V0 + A visible)

        {
            // ---- P_C0: C0 = K * V0^T -> fp32 (stride 65: conflict-free solve reads) ----
            f32x4 cacc[2];
            cacc[0] = (f32x4){0.f, 0.f, 0.f, 0.f};
            cacc[1] = (f32x4){0.f, 0.f, 0.f, 0.f};
            prod_cA(kah, kal, V0h_, V0l_, wn, cacc);
#pragma unroll
            for (int j = 0; j < 2; ++j)
#pragma unroll
                for (int rg = 0; rg < 4; ++rg) {
                    const int row = wm * 16 + kg * 4 + rg, col = wn * 32 + j * 16 + m16;
                    C032[row * 65 + col] = cacc[j][rg];
                }
        }
        __syncthreads();   // B3 (C032 visible; V0-LDS dead -> W writable by wave 0)

        // ---- next-chunk global prefetch: issue early, consume after B6 ----
        if (c + 1 < NCHUNK) issue_pf(c + 1);

        f32x4 yacc[2][2];   // custom-tile Y accumulators (waves != 0,4)

        if (wave == 0) {
            // zero the W region (union with V0; safe: V0 consumed before B3)
#pragma unroll
            for (int i0 = 0; i0 < 16; ++i0)
                ((uint4v*)Wh_)[i0 * 64 + lane] = (uint4v){0u, 0u, 0u, 0u};

            // ---- blocked solve: WAVE 0 ONLY, zero internal barriers ----
#pragma unroll
            for (int J = 0; J < 4; ++J) {
                float Nreg[16];
                if (J > 0) {
                    const int lo8 = lane * 8;
#pragma unroll
                    for (int band = 0; band < 4; ++band) {
                        f32x4 acc1 = (f32x4){0.f, 0.f, 0.f, 0.f};
#pragma unroll
                        for (int half = 0; half < 2; ++half) {
                            bf16x8 ah = *(const bf16x8*)&Ah_[(band * 2 + half) * SUBST + lo8];
                            bf16x8 al = *(const bf16x8*)&Al_[(band * 2 + half) * SUBST + lo8];
                            bf16x8 bh = *(const bf16x8*)&Wh_[(J * 2 + half) * SUBST + lo8];
                            bf16x8 bl = *(const bf16x8*)&Wl_[(J * 2 + half) * SUBST + lo8];
                            acc1 = __builtin_amdgcn_mfma_f32_16x16x32_bf16(al, bh, acc1, 0, 0, 0);
                            acc1 = __builtin_amdgcn_mfma_f32_16x16x32_bf16(ah, bl, acc1, 0, 0, 0);
                            acc1 = __builtin_amdgcn_mfma_f32_16x16x32_bf16(ah, bh, acc1, 0, 0, 0);
                        }
#pragma unroll
                        for (int rg = 0; rg < 4; ++rg)
                            N32[(band * 16 + kg * 4 + rg) * 17 + m16] = acc1[rg];
                    }
#pragma unroll
                    for (int j = 0; j < 16; ++j) Nreg[j] = N32[lane * 17 + j];
                }

                float Areg[16], CNreg[16];
                {
                    bf16x8 a0 = *(const bf16x8*)&Ah_[fidx(lane, 16 * J)];
                    bf16x8 a1 = *(const bf16x8*)&Ah_[fidx(lane, 16 * J + 8)];
                    bf16x8 b0 = *(const bf16x8*)&Al_[fidx(lane, 16 * J)];
                    bf16x8 b1 = *(const bf16x8*)&Al_[fidx(lane, 16 * J + 8)];
#pragma unroll
                    for (int e = 0; e < 8; ++e) {
                        Areg[e]     = bf2f((ushort)a0[e]) + bf2f((ushort)b0[e]);
                        Areg[e + 8] = bf2f((ushort)a1[e]) + bf2f((ushort)b1[e]);
                    }
#pragma unroll
                    for (int j = 0; j < 16; ++j) CNreg[j] = C032[lane * 65 + 16 * J + j];
                    if (J > 0) {
#pragma unroll
                        for (int j = 0; j < 16; ++j) CNreg[j] += Nreg[j];
                    }
                }
                float bvreg = bAll[s0 + 16 * J + m16];

                // 16 serial steps; even/odd partial sums halve the FMA chain depth
                float wreg[16];
#pragma unroll
                for (int j = 0; j < 16; ++j) {
                    float sA = CNreg[j], sB = 0.f;
#pragma unroll
                    for (int jj = 0; jj < 16; ++jj) {
                        if (jj < j) {
                            float pr = Areg[jj] * lane_bcast(wreg[jj], 16 * J + j);
                            if (jj & 1) sB += pr; else sA += pr;
                        }
                    }
                    float sum = sA + sB;
                    float beta_s = lane_bcast(bvreg, j);
                    wreg[j] = (lane > 16 * J + j) ? (-beta_s * sum) : 0.f;
                }

                // publish W columns J (octet stores)
                {
                    ushort8 h8[2], l8[2];
#pragma unroll
                    for (int e = 0; e < 16; ++e) {
                        ushort h = f2bf(wreg[e]);
                        h8[e >> 3][e & 7] = h;
                        l8[e >> 3][e & 7] = f2bf(wreg[e] - bf2f(h));
                    }
                    const int o0 = fidx(lane, 16 * J), o1 = fidx(lane, 16 * J + 8);
                    *(ushort8*)&Wh_[o0] = h8[0]; *(ushort8*)&Wh_[o1] = h8[1];
                    *(ushort8*)&Wl_[o0] = l8[0]; *(ushort8*)&Wl_[o1] = l8[1];
                }
            }
        } else {
            // ---- solve-window work: P_YM + P_QK on 6 waves (wave 4 idle so
            //      SIMD0 stays clear for the solver). 8 tiles over waves
            //      {1,2,3,5,6,7}: waves 1,2 take two tiles. ----
            const int nt_w = (wave == 4) ? 0 : ((wave <= 2) ? 2 : 1);
            const int wi = (wave < 4) ? (wave - 1) : (wave - 2);
#pragma unroll
            for (int ti = 0; ti < 2; ++ti) {
                if (ti >= nt_w) continue;
                const int T = (ti == 0) ? wi : (wi + 6);   // wave1:{0,6} wave2:{1,7}
                const int twm = T >> 1, twn = T & 1;
                bf16x8 qh2[2], ql2[2];
                load_af(Qh_, Ql_, twm, qh2, ql2);
                yacc[ti][0] = (f32x4){0.f, 0.f, 0.f, 0.f};
                yacc[ti][1] = (f32x4){0.f, 0.f, 0.f, 0.f};
                if (c > 0) prod_cA(qh2, ql2, MTh_, MTl_, twn, yacc[ti]);   // yacc = Q*M0
                // G = tril_(Q K^T); tiles entirely above the diagonal skip the product
                const bool gz = (twm * 16 + 15) <= (twn * 32);
                f32x4 ga[2];
                ga[0] = (f32x4){0.f, 0.f, 0.f, 0.f};
                ga[1] = (f32x4){0.f, 0.f, 0.f, 0.f};
                if (!gz) prod_cA(qh2, ql2, Kh_, Kl_, twn, ga);
#pragma unroll
                for (int j = 0; j < 2; ++j)
#pragma unroll
                    for (int rg = 0; rg < 4; ++rg) {
                        const int row = twm * 16 + kg * 4 + rg, col = twn * 32 + j * 16 + m16;
                        const float gv = (row > col) ? ga[j][rg] : 0.f;
                        const ushort h = f2bf(gv);
                        const int ii = fidx(row, col);
                        Gh_[ii] = h; Gl_[ii] = f2bf(gv - bf2f(h));
                    }
            }
        }
        __syncthreads();   // B4 (full W + G visible)

        {
            // ---- P_Delta: Delta = V0(reg) + W * K ; write DT = (beta Delta)^T ----
            f32x4 dacc[2];
            dacc[0] = V0acc[0]; dacc[1] = V0acc[1];
            bf16x8 wh2[2], wl2[2];
            load_af(Wh_, Wl_, wm, wh2, wl2);
            prod_cA(wh2, wl2, KTh_, KTl_, wn, dacc);
#pragma unroll
            for (int j = 0; j < 2; ++j)
#pragma unroll
                for (int rg = 0; rg < 4; ++rg) {
                    const int row = wm * 16 + kg * 4 + rg, col = wn * 32 + j * 16 + m16;
                    const float dv = dacc[j][rg] * bAll[s0 + row];   // beta_s * delta_s[d]
                    const ushort h = f2bf(dv);
                    const int ii = fidx(col, row);                   // DT[d][s]
                    DTh_[ii] = h; DTl_[ii] = f2bf(dv - bf2f(h));
                }
        }
        __syncthreads();   // B5 (DT ready)

        // ---- P_Y2: Y = yacc + G * DT^T -> global (custom tile map) ----
        if (wave != 0) {
            const int nt_w = (wave == 4) ? 0 : ((wave <= 2) ? 2 : 1);
            const int wi = (wave < 4) ? (wave - 1) : (wave - 2);
#pragma unroll
            for (int ti = 0; ti < 2; ++ti) {
                if (ti >= nt_w) continue;
                const int T = (ti == 0) ? wi : (wi + 6);
                const int twm = T >> 1, twn = T & 1;
                bf16x8 gh2[2], gl2[2];
                load_af(Gh_, Gl_, twm, gh2, gl2);
                prod_cA(gh2, gl2, DTh_, DTl_, twn, yacc[ti]);
#pragma unroll
                for (int j = 0; j < 2; ++j)
#pragma unroll
                    for (int rg = 0; rg < 4; ++rg) {
                        const int row = twm * 16 + kg * 4 + rg, col = twn * 32 + j * 16 + m16;
                        Yg[(size_t)(bS + s0 + row) * D_MODEL + nOff + col] = yacc[ti][j][rg];
                    }
            }
        }
        {
            // ---- P_M: Macc += K^T (beta Delta); state writeback (M + transposed MT) ----
            bf16x8 kth[2], ktl[2];
            load_af(KTh_, KTl_, wm, kth, ktl);
            prod_cA(kth, ktl, DTh_, DTl_, wn, Macc);
            if (c < NCHUNK - 1) {
#pragma unroll
                for (int j = 0; j < 2; ++j)
#pragma unroll
                    for (int rg = 0; rg < 4; ++rg) {
                        const int row = wm * 16 + kg * 4 + rg, col = wn * 32 + j * 16 + m16;
                        const float mv = Macc[j][rg];
                        const ushort h = f2bf(mv), l = f2bf(mv - bf2f(h));
                        const int ii = fidx(row, col);
                        Mh_[ii] = h; Ml_[ii] = l;
                        const int iT = fidx(col, row);   // MT = M^T, same fp32 value
                        MTh_[iT] = h; MTl_[iT] = l;
                    }
            }
        }
        __syncthreads();   // B6 (state + unions settled for next chunk)
    }
}

// ---------------------------------------------------------------------------
// RMSNorm. SPLIT=1: write fp16 for final GEMM. SPLIT=0: fp32 in place.
// ---------------------------------------------------------------------------
template <int SPLIT>
__global__ __launch_bounds__(256) void rmsnorm_kernel(float* __restrict__ Y,
                                                      const float* __restrict__ w,
                                                      unsigned short* __restrict__ H) {
    __shared__ float red[4];
    float* y = Y + (size_t)blockIdx.x * D_MODEL;
    const int t = threadIdx.x;
    const int wv = t >> 6, ln = t & 63;
    float4 v = ((float4*)y)[t];
    float ss = v.x * v.x + v.y * v.y + v.z * v.z + v.w * v.w;
#pragma unroll
    for (int off = 32; off; off >>= 1) ss += __shfl_xor(ss, off);
    if (ln == 0) red[wv] = ss;
    __syncthreads();
    float tot = red[0] + red[1] + red[2] + red[3];
    float inv = 1.f / sqrtf(tot * (1.f / D_MODEL) + 1e-6f);
    const float4 wv4 = ((const float4*)w)[t];
    v.x *= inv * wv4.x; v.y *= inv * wv4.y;
    v.z *= inv * wv4.z; v.w *= inv * wv4.w;
    if (SPLIT) {
        us4 h;
        h.x = f2h(v.x); h.y = f2h(v.y); h.z = f2h(v.z); h.w = f2h(v.w);
        size_t i = (size_t)blockIdx.x * 256 + t;
        ((us4*)H)[i] = h;
    } else {
        ((float4*)y)[t] = v;
    }
}

// ---------------------------------------------------------------------------
extern "C" void kernel_launch(void* const* d_in, const int* in_sizes, int n_in,
                              void* d_out, int out_size, void* d_ws, size_t ws_size,
                              hipStream_t stream) {
    const float* x     = (const float*)d_in[0];
    const float* Wq    = (const float*)d_in[1];
    const float* Wk    = (const float*)d_in[2];
    const float* Wv    = (const float*)d_in[3];
    const float* Wb    = (const float*)d_in[4];
    const float* Wo    = (const float*)d_in[5];
    const float* rms_w = (const float*)d_in[6];
    float* out = (float*)d_out;

    char* p = (char*)d_ws;
    float* Q  = (float*)p;  p += (size_t)RD * 4;
    float* Kp = (float*)p;  p += (size_t)RD * 4;
    float* Vp = (float*)p;  p += (size_t)RD * 4;
    float* Y  = (float*)p;  p += (size_t)RD * 4;
    float* Bt = (float*)p;  p += (size_t)32768 * 4;
    unsigned short* xh  = (unsigned short*)p;  p += (size_t)RD * 2;   // fp16; reused as Yh
    unsigned short* xl  = (unsigned short*)p;  p += (size_t)RD * 2;   // unused in fast path
    unsigned short* Wsh = (unsigned short*)p;  p += (size_t)WSZ * 2;
    unsigned short* Wsl = (unsigned short*)p;  p += (size_t)WSZ * 2;  // holds Wo-fp16
    const size_t need_fast = (size_t)RD * 16 + 131072 + (size_t)RD * 4 + (size_t)WSZ * 4;
    const bool fast = ws_size >= need_fast;

    // Wk/Wv fp16 conversions parked in Y (dead until scan writes it);
    // Wo-fp16 parked in Wsl (never otherwise touched in fast path).
    unsigned short* Wkh = (unsigned short*)Y;
    unsigned short* Wvh = Wkh + WSZ;
    unsigned short* Woh = Wsl;

    (void)hipFuncSetAttribute(reinterpret_cast<const void*>(scan_chunked),
                              hipFuncAttributeMaxDynamicSharedMemorySize, SMEM_SCAN);

    if (fast) {
        dim3 ggrid(D_MODEL / 64, ROWS / 128);       // (16,16) = 256 blocks
        dim3 qgrid(D_MODEL / 64, ROWS / 128, 3);    // 768 blocks = 3/CU
        split_kernel<<<RD / 4 / 256, 256, 0, stream>>>(x, xh, RD / 4);
        split4_kernel<<<WSZ / 256, 256, 0, stream>>>(Wq, Wk, Wv, Wo,
                                                     Wsh, Wkh, Wvh, Woh);
        gemm_qkv<<<qgrid, 256, 0, stream>>>(xh, Wsh, Wkh, Wvh, Q, Kp, Vp);
        beta_kernel<<<ROWS / 4, 256, 0, stream>>>(x, Wb, Bt);
        scan_chunked<<<BATCH * NHEAD, 512, SMEM_SCAN, stream>>>(Q, Kp, Vp, Bt, Y);
        rmsnorm_kernel<1><<<ROWS, 256, 0, stream>>>(Y, rms_w, xh);
        gemm_f16s<0><<<ggrid, 256, 0, stream>>>(xh, Woh, out, ROWS, D_MODEL, D_MODEL);
    } else {
        dim3 ggrid(D_MODEL / 128, ROWS / 128);  // (8,16)
        gemm_mfma<1><<<ggrid, 256, 0, stream>>>(x, Wq, Q, ROWS, D_MODEL, D_MODEL);
        gemm_mfma<1><<<ggrid, 256, 0, stream>>>(x, Wk, Kp, ROWS, D_MODEL, D_MODEL);
        gemm_mfma<1><<<ggrid, 256, 0, stream>>>(x, Wv, Vp, ROWS, D_MODEL, D_MODEL);
        beta_kernel<<<ROWS / 4, 256, 0, stream>>>(x, Wb, Bt);
        norm_qk<<<2 * ROWS * NHEAD / 4, 256, 0, stream>>>(Q, Kp);
        scan_chunked<<<BATCH * NHEAD, 512, SMEM_SCAN, stream>>>(Q, Kp, Vp, Bt, Y);
        rmsnorm_kernel<0><<<ROWS, 256, 0, stream>>>(Y, rms_w, nullptr);
        gemm_mfma<0><<<ggrid, 256, 0, stream>>>(Y, Wo, out, ROWS, D_MODEL, D_MODEL);
    }
}